// Round 3
// baseline (263.704 us; speedup 1.0000x reference)
//
#include <hip/hip_runtime.h>
#include <cstdint>
#include <cstddef>

// Geometry fixed by reference: B=32, C=3, H=384, W=512
#define HW 196608
#define NBATCH 32
#define NPIX (NBATCH*HW)          // 6,291,456
#define PID 98304u                // int(HW * 0.5)
#define THRESHF 0.1f
#define BLOCKS_PER_ROW 192        // HW / (256 threads * 4 px)
#define NBLOCKS (NBATCH*BLOCKS_PER_ROW)  // 6144
#define SC 4294967296.0           // 2^32 fixed-point scale
#define INVSC (1.0/4294967296.0)

// Order-preserving float <-> uint key (no NaNs here: dp clamped before acos)
__device__ __forceinline__ uint32_t f2key(float f) {
  uint32_t b = __float_as_uint(f);
  return b ^ ((b & 0x80000000u) ? 0xFFFFFFFFu : 0x80000000u);
}
__device__ __forceinline__ float key2f(uint32_t k) {
  uint32_t b = (k & 0x80000000u) ? (k ^ 0x80000000u) : ~k;
  return __uint_as_float(b);
}

// Pass 0: theta per pixel (float4), write theta, level-0 COUNT histogram
// (11 bits: key>>21). The clamp point-masses (dp outside +/-(1-eps), a large
// fraction of pixels, all mapping to the exact same two floats) are counted
// in registers and wave-reduced into their two bins — avoids same-address
// LDS atomic serialization.
// Dead-code note: reference clamps dp in fp32 BEFORE acos_safe with the same
// constant the branch tests via <=, so theta == acosf(clamp(dp)) exactly.
__global__ __launch_bounds__(256) void ep_pass0(
    const float* __restrict__ yhat, const float* __restrict__ yt,
    float* __restrict__ theta, uint32_t* __restrict__ cnt0) {
  __shared__ uint32_t hc[2048];
  const int t = threadIdx.x;
  for (int i = t; i < 2048; i += 256) hc[i] = 0;
  __syncthreads();
  const int b = blockIdx.x / BLOCKS_PER_ROW;
  const int inRow = blockIdx.x - b * BLOCKS_PER_ROW;
  const int hw = inRow * 1024 + t * 4;
  const float* yb = yhat + (size_t)b * 3 * HW + hw;
  const float* tb = yt   + (size_t)b * 3 * HW + hw;
  float4 a0 = *(const float4*)(yb);
  float4 a1 = *(const float4*)(yb + HW);
  float4 a2 = *(const float4*)(yb + 2 * HW);
  float4 t0 = *(const float4*)(tb);
  float4 t1 = *(const float4*)(tb + HW);
  float4 t2 = *(const float4*)(tb + 2 * HW);
  const float CHI = (float)( 1.0 - 1e-7);   // 0x3F7FFFFE
  const float CLO = (float)(-1.0 + 1e-7);
  const float thMin = acosf(CHI);           // uniform consts (compiler folds)
  const float thMax = acosf(CLO);
  float4 th4;
  uint32_t cMin = 0, cMax = 0;
#pragma unroll
  for (int j = 0; j < 4; j++) {
    float x0 = (&a0.x)[j], x1 = (&a1.x)[j], x2 = (&a2.x)[j];
    float y0 = (&t0.x)[j], y1 = (&t1.x)[j], y2 = (&t2.x)[j];
    float mag = sqrtf(x0 * x0 + x1 * x1 + x2 * x2);
    float dp = (x0 / mag) * y0 + (x1 / mag) * y1 + (x2 / mag) * y2;
    float dpc = fminf(fmaxf(dp, CLO), CHI);
    float th = acosf(dpc);
    (&th4.x)[j] = th;
    if (dp >= CHI)       cMin++;           // th == thMin exactly
    else if (dp <= CLO)  cMax++;           // th == thMax exactly
    else atomicAdd(&hc[f2key(th) >> 21], 1u);
  }
  *(float4*)(theta + (size_t)b * HW + hw) = th4;
  // wave-reduce clamp counts, one LDS atomic per wave per side
  for (int off = 32; off; off >>= 1) {
    cMin += __shfl_down(cMin, off);
    cMax += __shfl_down(cMax, off);
  }
  if ((t & 63) == 0) {
    if (cMin) atomicAdd(&hc[f2key(thMin) >> 21], cMin);
    if (cMax) atomicAdd(&hc[f2key(thMax) >> 21], cMax);
  }
  __syncthreads();
  for (int i = t; i < 2048; i += 256) {
    uint32_t c = hc[i];
    if (c) atomicAdd(&cnt0[b * 2048 + i], c);
  }
}

// Radix COUNT histogram: among keys matching prefix (>>matchShift), histogram
// the next digit. Only a tiny fraction of elements match -> few atomics.
template <int NBINS>
__global__ __launch_bounds__(256) void ep_radix(
    const float* __restrict__ theta, const uint32_t* __restrict__ keyp,
    uint32_t* __restrict__ cnt, int matchShift, int digShift) {
  __shared__ uint32_t hc[NBINS];
  const int t = threadIdx.x;
  for (int i = t; i < NBINS; i += 256) hc[i] = 0;
  __syncthreads();
  const int b = blockIdx.x / BLOCKS_PER_ROW;
  const int inRow = blockIdx.x - b * BLOCKS_PER_ROW;
  const int hw = inRow * 1024 + t * 4;
  float4 v = *(const float4*)(theta + (size_t)b * HW + hw);
  const uint32_t match = keyp[b] >> matchShift;
#pragma unroll
  for (int j = 0; j < 4; j++) {
    uint32_t key = f2key((&v.x)[j]);
    if ((key >> matchShift) == match)
      atomicAdd(&hc[(key >> digShift) & (NBINS - 1)], 1u);
  }
  __syncthreads();
  for (int i = t; i < NBINS; i += 256) {
    uint32_t c = hc[i];
    if (c) atomicAdd(&cnt[b * NBINS + i], c);
  }
}

// Scan one level's per-row count histogram: find bin containing k-th element,
// update krem, extend key prefix. Grid = 32 rows.
__global__ __launch_bounds__(256) void ep_scan(
    const uint32_t* __restrict__ cnt, uint32_t* __restrict__ keyp,
    uint32_t* __restrict__ krem, int nbins, int shift, int first) {
  const int b = blockIdx.x;
  const int t = threadIdx.x;
  const int bpt = nbins >> 8;
  const uint32_t* c = cnt + (size_t)b * nbins;
  const int base = t * bpt;
  uint32_t csum = 0;
  for (int i = 0; i < bpt; i++) csum += c[base + i];
  __shared__ uint32_t lc[256];
  lc[t] = csum;
  __syncthreads();
  uint32_t ci = csum;
  for (int off = 1; off < 256; off <<= 1) {
    uint32_t cp = (t >= off) ? lc[t - off] : 0;
    __syncthreads();
    ci += cp;
    lc[t] = ci;
    __syncthreads();
  }
  const uint32_t cumBefore = ci - csum;
  const uint32_t k = first ? PID : krem[b];
  if (k >= cumBefore && k < ci) {   // unique owner thread
    uint32_t cb = cumBefore;
    int sel = base;
    for (int i = 0; i < bpt; i++) {
      uint32_t cc = c[base + i];
      if (cb + cc > k) { sel = base + i; break; }
      cb += cc;
    }
    krem[b] = k - cb;
    uint32_t kp = first ? 0u : keyp[b];
    keyp[b] = kp | ((uint32_t)sel << shift);
  }
}

// Final pass: with exact kth key known, accumulate per-row
//   cnt_less, sum_less (key < kth), sum_thr (theta < 0.1)
// via register/wave/block reduction + one native u64 fixed-point atomic each.
__global__ __launch_bounds__(256) void ep_final(
    const float* __restrict__ theta, const uint32_t* __restrict__ keyp,
    uint32_t* __restrict__ cnt_less, unsigned long long* __restrict__ sum_less,
    unsigned long long* __restrict__ thrsum) {
  const int t = threadIdx.x;
  const int b = blockIdx.x / BLOCKS_PER_ROW;
  const int inRow = blockIdx.x - b * BLOCKS_PER_ROW;
  const int hw = inRow * 1024 + t * 4;
  float4 v = *(const float4*)(theta + (size_t)b * HW + hw);
  const uint32_t kk = keyp[b];
  uint32_t cl = 0;
  double sl = 0.0, st = 0.0;
#pragma unroll
  for (int j = 0; j < 4; j++) {
    float f = (&v.x)[j];
    uint32_t key = f2key(f);
    if (key < kk) { cl++; sl += (double)f; }
    if (f < THRESHF) st += (double)f;
  }
  for (int off = 32; off; off >>= 1) {
    cl += __shfl_down(cl, off);
    sl += __shfl_down(sl, off);
    st += __shfl_down(st, off);
  }
  __shared__ uint32_t s_cl[4];
  __shared__ double s_sl[4], s_st[4];
  const int wave = t >> 6, lane = t & 63;
  if (lane == 0) { s_cl[wave] = cl; s_sl[wave] = sl; s_st[wave] = st; }
  __syncthreads();
  if (t == 0) {
    uint32_t CL = s_cl[0] + s_cl[1] + s_cl[2] + s_cl[3];
    double SL = s_sl[0] + s_sl[1] + s_sl[2] + s_sl[3];
    double ST = s_st[0] + s_st[1] + s_st[2] + s_st[3];
    if (CL) atomicAdd(&cnt_less[b], CL);
    if (SL != 0.0) atomicAdd(&sum_less[b], (unsigned long long)(SL * SC));
    if (ST != 0.0) atomicAdd(&thrsum[b], (unsigned long long)(ST * SC));
  }
}

__global__ void ep_out(const uint32_t* __restrict__ keyp,
                       const unsigned long long* __restrict__ sum_less,
                       const unsigned long long* __restrict__ thrsum,
                       const uint32_t* __restrict__ cnt_less,
                       float* __restrict__ out) {
  const int b = threadIdx.x;  // one wave; rows on lanes 0..31
  double v = 0.0;
  if (b < NBATCH) {
    float fk = key2f(keyp[b]);
    if (fk < THRESHF)
      v = (double)sum_less[b] * INVSC + (double)(PID - cnt_less[b]) * (double)fk;
    else
      v = (double)thrsum[b] * INVSC;
  }
  for (int off = 32; off; off >>= 1) v += __shfl_down(v, off);
  if (b == 0) out[0] = (float)v;
}

extern "C" void kernel_launch(void* const* d_in, const int* in_sizes, int n_in,
                              void* d_out, int out_size, void* d_ws, size_t ws_size,
                              hipStream_t stream) {
  const float* yhat = (const float*)d_in[0];
  const float* yt   = (const float*)d_in[1];
  float* out = (float*)d_out;

  char* w = (char*)d_ws;
  float* theta = (float*)w;
  size_t off = (size_t)NPIX * 4;
  uint32_t* cnt0 = (uint32_t*)(w + off); off += 32 * 2048 * 4;
  uint32_t* cnt1 = (uint32_t*)(w + off); off += 32 * 2048 * 4;
  uint32_t* cnt2 = (uint32_t*)(w + off); off += 32 * 1024 * 4;
  unsigned long long* sum_less = (unsigned long long*)(w + off); off += 32 * 8;
  unsigned long long* thrsum   = (unsigned long long*)(w + off); off += 32 * 8;
  uint32_t* keyp     = (uint32_t*)(w + off); off += 32 * 4;
  uint32_t* krem     = (uint32_t*)(w + off); off += 32 * 4;
  uint32_t* cnt_less = (uint32_t*)(w + off); off += 32 * 4;

  const size_t state_start = (size_t)NPIX * 4;
  hipMemsetAsync(w + state_start, 0, off - state_start, stream);

  ep_pass0<<<NBLOCKS, 256, 0, stream>>>(yhat, yt, theta, cnt0);
  ep_scan<<<32, 256, 0, stream>>>(cnt0, keyp, krem, 2048, 21, 1);
  ep_radix<2048><<<NBLOCKS, 256, 0, stream>>>(theta, keyp, cnt1, 21, 10);
  ep_scan<<<32, 256, 0, stream>>>(cnt1, keyp, krem, 2048, 10, 0);
  ep_radix<1024><<<NBLOCKS, 256, 0, stream>>>(theta, keyp, cnt2, 10, 0);
  ep_scan<<<32, 256, 0, stream>>>(cnt2, keyp, krem, 1024, 0, 0);
  ep_final<<<NBLOCKS, 256, 0, stream>>>(theta, keyp, cnt_less, sum_less, thrsum);
  ep_out<<<1, 64, 0, stream>>>(keyp, sum_less, thrsum, cnt_less, out);
}

// Round 8
// 219.288 us; speedup vs baseline: 1.2025x; 1.2025x over previous
//
#include <hip/hip_runtime.h>
#include <cstdint>
#include <cstddef>

// Geometry fixed by reference: B=32, C=3, H=384, W=512
#define HW 196608
#define NBATCH 32
#define NPIX (NBATCH*HW)          // 6,291,456
#define PID 98304u                // int(HW * 0.5)
#define THRESHF 0.1f
#define BLOCKS_PER_ROW 192        // HW / (256 threads * 4 px)
#define NBLOCKS (NBATCH*BLOCKS_PER_ROW)  // 6144

// Order-preserving float <-> uint key (no NaNs here: dp clamped before acos)
__device__ __forceinline__ uint32_t f2key(float f) {
  uint32_t b = __float_as_uint(f);
  return b ^ ((b & 0x80000000u) ? 0xFFFFFFFFu : 0x80000000u);
}
__device__ __forceinline__ float key2f(uint32_t k) {
  uint32_t b = (k & 0x80000000u) ? (k ^ 0x80000000u) : ~k;
  return __uint_as_float(b);
}

// Pass 0: theta per pixel (float4), write theta, level-0 COUNT histogram
// (11 bits: key>>21). Clamp point-masses (dp outside +/-(1-eps); a large
// fraction of pixels, all mapping to the same two floats) are counted in
// registers and wave-reduced — avoids same-address LDS atomic serialization.
// Dead-code note: reference clamps dp in fp32 BEFORE acos_safe with the same
// constant the branch tests via <=, so theta == acosf(clamp(dp)) exactly.
__global__ __launch_bounds__(256) void ep_pass0(
    const float* __restrict__ yhat, const float* __restrict__ yt,
    float* __restrict__ theta, uint32_t* __restrict__ cnt0) {
  __shared__ uint32_t hc[2048];
  const int t = threadIdx.x;
  for (int i = t; i < 2048; i += 256) hc[i] = 0;
  __syncthreads();
  const int b = blockIdx.x / BLOCKS_PER_ROW;
  const int inRow = blockIdx.x - b * BLOCKS_PER_ROW;
  const int hw = inRow * 1024 + t * 4;
  const float* yb = yhat + (size_t)b * 3 * HW + hw;
  const float* tb = yt   + (size_t)b * 3 * HW + hw;
  float4 a0 = *(const float4*)(yb);
  float4 a1 = *(const float4*)(yb + HW);
  float4 a2 = *(const float4*)(yb + 2 * HW);
  float4 t0 = *(const float4*)(tb);
  float4 t1 = *(const float4*)(tb + HW);
  float4 t2 = *(const float4*)(tb + 2 * HW);
  const float CHI = (float)( 1.0 - 1e-7);   // 0x3F7FFFFE
  const float CLO = (float)(-1.0 + 1e-7);
  const float thMin = acosf(CHI);           // uniform consts (compiler folds)
  const float thMax = acosf(CLO);
  float4 th4;
  uint32_t cMin = 0, cMax = 0;
#pragma unroll
  for (int j = 0; j < 4; j++) {
    float x0 = (&a0.x)[j], x1 = (&a1.x)[j], x2 = (&a2.x)[j];
    float y0 = (&t0.x)[j], y1 = (&t1.x)[j], y2 = (&t2.x)[j];
    float mag = sqrtf(x0 * x0 + x1 * x1 + x2 * x2);
    float dp = (x0 / mag) * y0 + (x1 / mag) * y1 + (x2 / mag) * y2;
    float dpc = fminf(fmaxf(dp, CLO), CHI);
    float th = acosf(dpc);
    (&th4.x)[j] = th;
    if (dp >= CHI)       cMin++;           // th == thMin exactly
    else if (dp <= CLO)  cMax++;           // th == thMax exactly
    else atomicAdd(&hc[f2key(th) >> 21], 1u);
  }
  *(float4*)(theta + (size_t)b * HW + hw) = th4;
  for (int off = 32; off; off >>= 1) {
    cMin += __shfl_down(cMin, off);
    cMax += __shfl_down(cMax, off);
  }
  if ((t & 63) == 0) {
    if (cMin) atomicAdd(&hc[f2key(thMin) >> 21], cMin);
    if (cMax) atomicAdd(&hc[f2key(thMax) >> 21], cMax);
  }
  __syncthreads();
  for (int i = t; i < 2048; i += 256) {
    uint32_t c = hc[i];
    if (c) atomicAdd(&cnt0[b * 2048 + i], c);
  }
}

// Radix COUNT histogram: among keys matching prefix (>>matchShift), histogram
// the next digit. Only a small fraction of elements match -> few atomics.
template <int NBINS>
__global__ __launch_bounds__(256) void ep_radix(
    const float* __restrict__ theta, const uint32_t* __restrict__ keyp,
    uint32_t* __restrict__ cnt, int matchShift, int digShift) {
  __shared__ uint32_t hc[NBINS];
  const int t = threadIdx.x;
  for (int i = t; i < NBINS; i += 256) hc[i] = 0;
  __syncthreads();
  const int b = blockIdx.x / BLOCKS_PER_ROW;
  const int inRow = blockIdx.x - b * BLOCKS_PER_ROW;
  const int hw = inRow * 1024 + t * 4;
  float4 v = *(const float4*)(theta + (size_t)b * HW + hw);
  const uint32_t match = keyp[b] >> matchShift;
#pragma unroll
  for (int j = 0; j < 4; j++) {
    uint32_t key = f2key((&v.x)[j]);
    if ((key >> matchShift) == match)
      atomicAdd(&hc[(key >> digShift) & (NBINS - 1)], 1u);
  }
  __syncthreads();
  for (int i = t; i < NBINS; i += 256) {
    uint32_t c = hc[i];
    if (c) atomicAdd(&cnt[b * NBINS + i], c);
  }
}

// Scan one level's per-row count histogram: find bin containing k-th element,
// update krem, extend key prefix. Grid = 32 rows.
__global__ __launch_bounds__(256) void ep_scan(
    const uint32_t* __restrict__ cnt, uint32_t* __restrict__ keyp,
    uint32_t* __restrict__ krem, int nbins, int shift, int first) {
  const int b = blockIdx.x;
  const int t = threadIdx.x;
  const int bpt = nbins >> 8;
  const uint32_t* c = cnt + (size_t)b * nbins;
  const int base = t * bpt;
  uint32_t csum = 0;
  for (int i = 0; i < bpt; i++) csum += c[base + i];
  __shared__ uint32_t lc[256];
  lc[t] = csum;
  __syncthreads();
  uint32_t ci = csum;
  for (int off = 1; off < 256; off <<= 1) {
    uint32_t cp = (t >= off) ? lc[t - off] : 0;
    __syncthreads();
    ci += cp;
    lc[t] = ci;
    __syncthreads();
  }
  const uint32_t cumBefore = ci - csum;
  const uint32_t k = first ? PID : krem[b];
  if (k >= cumBefore && k < ci) {   // unique owner thread
    uint32_t cb = cumBefore;
    int sel = base;
    for (int i = 0; i < bpt; i++) {
      uint32_t cc = c[base + i];
      if (cb + cc > k) { sel = base + i; break; }
      cb += cc;
    }
    krem[b] = k - cb;
    uint32_t kp = first ? 0u : keyp[b];
    keyp[b] = kp | ((uint32_t)sel << shift);
  }
}

// Final pass: with exact kth key known, per-block partials of
//   cnt_less (key < kth), sum_less (key < kth), sum_thr (theta < 0.1)
// written to DISTINCT slots — zero atomics, zero contention.
__global__ __launch_bounds__(256) void ep_final(
    const float* __restrict__ theta, const uint32_t* __restrict__ keyp,
    uint32_t* __restrict__ part_cl, double* __restrict__ part_sl,
    double* __restrict__ part_st) {
  const int t = threadIdx.x;
  const int b = blockIdx.x / BLOCKS_PER_ROW;
  const int inRow = blockIdx.x - b * BLOCKS_PER_ROW;
  const int hw = inRow * 1024 + t * 4;
  float4 v = *(const float4*)(theta + (size_t)b * HW + hw);
  const uint32_t kk = keyp[b];
  uint32_t cl = 0;
  double sl = 0.0, st = 0.0;
#pragma unroll
  for (int j = 0; j < 4; j++) {
    float f = (&v.x)[j];
    uint32_t key = f2key(f);
    if (key < kk) { cl++; sl += (double)f; }
    if (f < THRESHF) st += (double)f;
  }
  for (int off = 32; off; off >>= 1) {
    cl += __shfl_down(cl, off);
    sl += __shfl_down(sl, off);
    st += __shfl_down(st, off);
  }
  __shared__ uint32_t s_cl[4];
  __shared__ double s_sl[4], s_st[4];
  const int wave = t >> 6, lane = t & 63;
  if (lane == 0) { s_cl[wave] = cl; s_sl[wave] = sl; s_st[wave] = st; }
  __syncthreads();
  if (t == 0) {
    part_cl[blockIdx.x] = s_cl[0] + s_cl[1] + s_cl[2] + s_cl[3];
    part_sl[blockIdx.x] = s_sl[0] + s_sl[1] + s_sl[2] + s_sl[3];
    part_st[blockIdx.x] = s_st[0] + s_st[1] + s_st[2] + s_st[3];
  }
}

// Merged reduce + output: 1 block of 1024 threads = 16 WAVES (wave=64 on CDNA!).
// Wave w reduces rows w and w+16 (192 partials each); then wave 0 combines the
// 32 per-row values into the scalar.
__global__ __launch_bounds__(1024) void ep_out(
    const uint32_t* __restrict__ keyp, const uint32_t* __restrict__ part_cl,
    const double* __restrict__ part_sl, const double* __restrict__ part_st,
    float* __restrict__ out) {
  const int t = threadIdx.x;
  const int w = t >> 6, lane = t & 63;   // 16 waves of 64 lanes
  __shared__ double sv[32];
  for (int r = w; r < NBATCH; r += 16) {
    uint32_t cl = 0;
    double sl = 0.0, st = 0.0;
    for (int i = lane; i < BLOCKS_PER_ROW; i += 64) {
      int idx = r * BLOCKS_PER_ROW + i;
      cl += part_cl[idx];
      sl += part_sl[idx];
      st += part_st[idx];
    }
    for (int off = 32; off; off >>= 1) {
      cl += __shfl_down(cl, off);
      sl += __shfl_down(sl, off);
      st += __shfl_down(st, off);
    }
    if (lane == 0) {
      float fk = key2f(keyp[r]);
      if (fk < THRESHF)
        sv[r] = sl + (double)(PID - cl) * (double)fk;  // smallest-PID branch (ties at fk)
      else
        sv[r] = st;                                    // below-threshold branch
    }
  }
  __syncthreads();
  if (w == 0) {                       // all 64 lanes of wave 0 participate
    double v = (lane < NBATCH) ? sv[lane] : 0.0;
    for (int off = 32; off; off >>= 1) v += __shfl_down(v, off);
    if (lane == 0) out[0] = (float)v;
  }
}

extern "C" void kernel_launch(void* const* d_in, const int* in_sizes, int n_in,
                              void* d_out, int out_size, void* d_ws, size_t ws_size,
                              hipStream_t stream) {
  const float* yhat = (const float*)d_in[0];
  const float* yt   = (const float*)d_in[1];
  float* out = (float*)d_out;

  char* w = (char*)d_ws;
  float* theta = (float*)w;
  size_t off = (size_t)NPIX * 4;
  uint32_t* cnt0 = (uint32_t*)(w + off); off += 32 * 2048 * 4;
  uint32_t* cnt1 = (uint32_t*)(w + off); off += 32 * 2048 * 4;
  uint32_t* cnt2 = (uint32_t*)(w + off); off += 32 * 1024 * 4;
  const size_t hist_end = off;               // memset covers cnt0..cnt2 only
  uint32_t* keyp = (uint32_t*)(w + off); off += 32 * 4;
  uint32_t* krem = (uint32_t*)(w + off); off += 32 * 4;
  uint32_t* part_cl = (uint32_t*)(w + off); off += NBLOCKS * 4;
  double*   part_sl = (double*)(w + off);   off += NBLOCKS * 8;
  double*   part_st = (double*)(w + off);   off += NBLOCKS * 8;

  // zero only the atomic count histograms (keyp/krem/partials are
  // unconditionally written before being read)
  hipMemsetAsync(w + (size_t)NPIX * 4, 0, hist_end - (size_t)NPIX * 4, stream);

  ep_pass0<<<NBLOCKS, 256, 0, stream>>>(yhat, yt, theta, cnt0);
  ep_scan<<<32, 256, 0, stream>>>(cnt0, keyp, krem, 2048, 21, 1);
  ep_radix<2048><<<NBLOCKS, 256, 0, stream>>>(theta, keyp, cnt1, 21, 10);
  ep_scan<<<32, 256, 0, stream>>>(cnt1, keyp, krem, 2048, 10, 0);
  ep_radix<1024><<<NBLOCKS, 256, 0, stream>>>(theta, keyp, cnt2, 10, 0);
  ep_scan<<<32, 256, 0, stream>>>(cnt2, keyp, krem, 1024, 0, 0);
  ep_final<<<NBLOCKS, 256, 0, stream>>>(theta, keyp, part_cl, part_sl, part_st);
  ep_out<<<1, 1024, 0, stream>>>(keyp, part_cl, part_sl, part_st, out);
}

// Round 9
// 166.641 us; speedup vs baseline: 1.5825x; 1.3159x over previous
//
#include <hip/hip_runtime.h>
#include <cstdint>
#include <cstddef>

// Geometry fixed by reference: B=32, C=3, H=384, W=512
#define HW 196608
#define NBATCH 32
#define PID 98304u                // int(HW * 0.5)
#define THRESHF 0.1f
#define BLOCKS_PER_ROW 192        // HW / (256 threads * 4 px)
#define NBLOCKS (NBATCH*BLOCKS_PER_ROW)  // 6144

// Order-preserving float <-> uint key (no NaNs here: dp clamped before acos)
__device__ __forceinline__ uint32_t f2key(float f) {
  uint32_t b = __float_as_uint(f);
  return b ^ ((b & 0x80000000u) ? 0xFFFFFFFFu : 0x80000000u);
}
__device__ __forceinline__ float key2f(uint32_t k) {
  uint32_t b = (k & 0x80000000u) ? (k ^ 0x80000000u) : ~k;
  return __uint_as_float(b);
}

// theta == acosf(clamp(dp)): reference clamps dp in fp32 BEFORE acos_safe with
// the same constant the branch tests via <=, so the linearized branch is dead.
__device__ __forceinline__ void theta4(const float* __restrict__ yb,
                                       const float* __restrict__ tb,
                                       float th[4]) {
  float4 a0 = *(const float4*)(yb);
  float4 a1 = *(const float4*)(yb + HW);
  float4 a2 = *(const float4*)(yb + 2 * HW);
  float4 t0 = *(const float4*)(tb);
  float4 t1 = *(const float4*)(tb + HW);
  float4 t2 = *(const float4*)(tb + 2 * HW);
  const float CHI = (float)( 1.0 - 1e-7);
  const float CLO = (float)(-1.0 + 1e-7);
#pragma unroll
  for (int j = 0; j < 4; j++) {
    float x0 = (&a0.x)[j], x1 = (&a1.x)[j], x2 = (&a2.x)[j];
    float y0 = (&t0.x)[j], y1 = (&t1.x)[j], y2 = (&t2.x)[j];
    float mag = sqrtf(x0 * x0 + x1 * x1 + x2 * x2);
    float dp = (x0 / mag) * y0 + (x1 / mag) * y1 + (x2 / mag) * y2;
    dp = fminf(fmaxf(dp, CLO), CHI);
    th[j] = acosf(dp);
  }
}

// Pass 0: pure streaming. Per-block partials of {count(theta<T), sum(theta<T)}
// to DISTINCT slots. No LDS histogram, no theta store, no atomics.
__global__ __launch_bounds__(256) void ep_pass0(
    const float* __restrict__ yhat, const float* __restrict__ yt,
    uint32_t* __restrict__ part_cnt, double* __restrict__ part_sum) {
  const int t = threadIdx.x;
  const int b = blockIdx.x / BLOCKS_PER_ROW;
  const int inRow = blockIdx.x - b * BLOCKS_PER_ROW;
  const int hw = inRow * 1024 + t * 4;
  const float* yb = yhat + (size_t)b * 3 * HW + hw;
  const float* tb = yt   + (size_t)b * 3 * HW + hw;
  float th[4];
  theta4(yb, tb, th);
  uint32_t cnt = 0;
  float fsum = 0.f;
#pragma unroll
  for (int j = 0; j < 4; j++) {
    if (th[j] < THRESHF) { cnt++; fsum += th[j]; }
  }
  double s = (double)fsum;
  for (int off = 32; off; off >>= 1) {
    cnt += __shfl_down(cnt, off);
    s   += __shfl_down(s, off);
  }
  __shared__ uint32_t s_c[4];
  __shared__ double   s_s[4];
  const int wave = t >> 6, lane = t & 63;
  if (lane == 0) { s_c[wave] = cnt; s_s[wave] = s; }
  __syncthreads();
  if (t == 0) {
    part_cnt[blockIdx.x] = s_c[0] + s_c[1] + s_c[2] + s_c[3];
    part_sum[blockIdx.x] = s_s[0] + s_s[1] + s_s[2] + s_s[3];
  }
}

// Finish: one block per row. cond = (#{v<T} > PID)  <=>  vals[pid] < T (exact,
// tie-safe). cond false -> row answer is sum(v<T) (already reduced). cond true
// -> exact in-block 3-level radix select of vals[PID] (recomputing theta from
// inputs; no global sync needed since one workgroup owns the whole row).
__global__ __launch_bounds__(1024) void ep_finish(
    const float* __restrict__ yhat, const float* __restrict__ yt,
    const uint32_t* __restrict__ part_cnt, const double* __restrict__ part_sum,
    double* __restrict__ row_val) {
  const int b = blockIdx.x;
  const int t = threadIdx.x;
  const int w = t >> 6, lane = t & 63;       // 16 waves of 64

  // Phase A: reduce this row's 192 partials
  uint32_t c = 0; double s = 0.0;
  if (t < BLOCKS_PER_ROW) {
    c = part_cnt[b * BLOCKS_PER_ROW + t];
    s = part_sum[b * BLOCKS_PER_ROW + t];
  }
  for (int off = 32; off; off >>= 1) {
    c += __shfl_down(c, off);
    s += __shfl_down(s, off);
  }
  __shared__ uint32_t scl[16];
  __shared__ double   sdl[16];
  if (lane == 0) { scl[w] = c; sdl[w] = s; }
  __shared__ uint32_t sh_cnt;
  __shared__ double   sh_sum;
  __syncthreads();
  if (t == 0) {
    uint32_t C = 0; double S = 0.0;
    for (int i = 0; i < 16; i++) { C += scl[i]; S += sdl[i]; }
    sh_cnt = C; sh_sum = S;
  }
  __syncthreads();
  const bool cond = sh_cnt > PID;
  if (!cond) {
    if (t == 0) row_val[b] = sh_sum;
    return;
  }

  // Rare path: exact k-th (k=PID) order statistic of this row's thetas.
  const float* yb = yhat + (size_t)b * 3 * HW;
  const float* tb = yt   + (size_t)b * 3 * HW;
  __shared__ uint32_t hc[2048];
  __shared__ uint32_t lsc[1024];
  __shared__ uint32_t sh_prefix, sh_krem, sh_cless;
  if (t == 0) { sh_prefix = 0u; sh_krem = PID; sh_cless = 0u; }

  const int shifts[3] = {21, 10, 0};
  const int nbv[3]    = {2048, 2048, 1024};
  const int mshift[3] = {32, 21, 10};      // bits above current digit
  for (int lev = 0; lev < 3; lev++) {
    const int shift = shifts[lev];
    const int nbins = nbv[lev];
    for (int i = t; i < nbins; i += 1024) hc[i] = 0;
    __syncthreads();                        // also publishes sh_* updates
    const uint32_t pref = sh_prefix;
    const uint32_t k    = sh_krem;
    for (int p = t * 4; p < HW; p += 4096) {
      float th[4];
      theta4(yb + p, tb + p, th);
#pragma unroll
      for (int j = 0; j < 4; j++) {
        uint32_t key = f2key(th[j]);
        bool m = (lev == 0) || ((key >> mshift[lev]) == (pref >> mshift[lev]));
        if (m) atomicAdd(&hc[(key >> shift) & (nbins - 1)], 1u);
      }
    }
    __syncthreads();
    const int bpt = nbins >> 10;            // 2 or 1 bins per thread
    const int base = t * bpt;
    uint32_t csum = 0;
    for (int i = 0; i < bpt; i++) csum += hc[base + i];
    lsc[t] = csum;
    __syncthreads();
    uint32_t ci = csum;
    for (int off = 1; off < 1024; off <<= 1) {
      uint32_t cp = (t >= off) ? lsc[t - off] : 0;
      __syncthreads();
      ci += cp;
      lsc[t] = ci;
      __syncthreads();
    }
    const uint32_t cumBefore = ci - csum;
    if (k >= cumBefore && k < ci) {         // unique owner thread
      uint32_t cb = cumBefore;
      int sel = base;
      for (int i = 0; i < bpt; i++) {
        uint32_t cc = hc[base + i];
        if (cb + cc > k) { sel = base + i; break; }
        cb += cc;
      }
      sh_krem   = k - cb;
      sh_cless += cb;                       // owner-only RMW, barrier-separated
      sh_prefix = pref | ((uint32_t)sel << shift);
    }
    __syncthreads();
  }
  const uint32_t keystar  = sh_prefix;      // exact key of vals[PID]
  const uint32_t cnt_less = sh_cless;       // #{key < keystar}

  // Sum of values strictly below vals[PID]
  double sl = 0.0;
  for (int p = t * 4; p < HW; p += 4096) {
    float th[4];
    theta4(yb + p, tb + p, th);
#pragma unroll
    for (int j = 0; j < 4; j++)
      if (f2key(th[j]) < keystar) sl += (double)th[j];
  }
  for (int off = 32; off; off >>= 1) sl += __shfl_down(sl, off);
  if (lane == 0) sdl[w] = sl;
  __syncthreads();
  if (t == 0) {
    double SL = 0.0;
    for (int i = 0; i < 16; i++) SL += sdl[i];
    row_val[b] = SL + (double)(PID - cnt_less) * (double)key2f(keystar);
  }
}

// Combine 32 row values into the scalar output (one wave).
__global__ void ep_out(const double* __restrict__ row_val,
                       float* __restrict__ out) {
  const int lane = threadIdx.x;             // 64 threads = 1 wave
  double v = (lane < NBATCH) ? row_val[lane] : 0.0;
  for (int off = 32; off; off >>= 1) v += __shfl_down(v, off);
  if (lane == 0) out[0] = (float)v;
}

extern "C" void kernel_launch(void* const* d_in, const int* in_sizes, int n_in,
                              void* d_out, int out_size, void* d_ws, size_t ws_size,
                              hipStream_t stream) {
  const float* yhat = (const float*)d_in[0];
  const float* yt   = (const float*)d_in[1];
  float* out = (float*)d_out;

  // ws layout (all slots written before read -> no memset needed):
  //   part_sum[6144] f64 | row_val[32] f64 | part_cnt[6144] u32
  char* w = (char*)d_ws;
  double*   part_sum = (double*)w;
  double*   row_val  = part_sum + NBLOCKS;
  uint32_t* part_cnt = (uint32_t*)(row_val + NBATCH);

  ep_pass0 <<<NBLOCKS, 256, 0, stream>>>(yhat, yt, part_cnt, part_sum);
  ep_finish<<<NBATCH, 1024, 0, stream>>>(yhat, yt, part_cnt, part_sum, row_val);
  ep_out   <<<1, 64, 0, stream>>>(row_val, out);
}

// Round 12
// 165.084 us; speedup vs baseline: 1.5974x; 1.0094x over previous
//
#include <hip/hip_runtime.h>
#include <cstdint>
#include <cstddef>

// Geometry fixed by reference: B=32, C=3, H=384, W=512
#define HW 196608
#define NBATCH 32
#define PID 98304u                // int(HW * 0.5)
#define THRESHF 0.1f
#define BLOCKS_PER_ROW 192        // HW / (256 threads * 4 px)
#define NBLOCKS (NBATCH*BLOCKS_PER_ROW)  // 6144

#define CHIF 0.99999988079071044921875f   // (float)(1.0 - 1e-7), 0x3F7FFFFE
#define CLOF (-0.99999988079071044921875f)
// theta < 0.1 requires dp > cos(0.1)=0.9950042; SPLIT is conservative:
// acosf(0.9949) = 0.10098 > 0.1, so dp <= SPLIT can never be selected.
#define SPLITF 0.9949f

// Order-preserving float <-> uint key (no NaNs here: dp clamped before acos)
__device__ __forceinline__ uint32_t f2key(float f) {
  uint32_t b = __float_as_uint(f);
  return b ^ ((b & 0x80000000u) ? 0xFFFFFFFFu : 0x80000000u);
}
__device__ __forceinline__ float key2f(uint32_t k) {
  uint32_t b = (k & 0x80000000u) ? (k ^ 0x80000000u) : ~k;
  return __uint_as_float(b);
}

// dp = dot(a,y) * rsqrt(dot(a,a)) — v_rsq_f32 + mul replaces sqrt + 3 IEEE
// divides (~1 ulp dp error; selection-boundary impact << absmax budget).
__device__ __forceinline__ void dp4(const float* __restrict__ yb,
                                    const float* __restrict__ tb,
                                    float dp[4]) {
  float4 a0 = *(const float4*)(yb);
  float4 a1 = *(const float4*)(yb + HW);
  float4 a2 = *(const float4*)(yb + 2 * HW);
  float4 t0 = *(const float4*)(tb);
  float4 t1 = *(const float4*)(tb + HW);
  float4 t2 = *(const float4*)(tb + 2 * HW);
#pragma unroll
  for (int j = 0; j < 4; j++) {
    float x0 = (&a0.x)[j], x1 = (&a1.x)[j], x2 = (&a2.x)[j];
    float y0 = (&t0.x)[j], y1 = (&t1.x)[j], y2 = (&t2.x)[j];
    float mag2 = fmaf(x0, x0, fmaf(x1, x1, x2 * x2));
    float dot  = fmaf(x0, y0, fmaf(x1, y1, x2 * y2));
    dp[j] = dot * __builtin_amdgcn_rsqf(mag2);
  }
}

// Full theta (rare radix path only): reference clamps dp in fp32 BEFORE
// acos_safe with the same constant the branch tests via <=, so the
// linearized branch is dead code: theta == acosf(clamp(dp)).
__device__ __forceinline__ void theta4(const float* __restrict__ yb,
                                       const float* __restrict__ tb,
                                       float th[4]) {
  float dp[4];
  dp4(yb, tb, dp);
#pragma unroll
  for (int j = 0; j < 4; j++)
    th[j] = acosf(fminf(fmaxf(dp[j], CLOF), CHIF));
}

// Pass 0: pure streaming. Per-block partials of {count(theta<T), sum(theta<T)}
// to DISTINCT slots. acosf only for the sliver dp in (SPLIT, CHI):
//   dp >= CHI  -> theta == thMin (constant), counts, no acos
//   dp <= SPLIT-> theta > 0.10098, never selected, no acos
__global__ __launch_bounds__(256) void ep_pass0(
    const float* __restrict__ yhat, const float* __restrict__ yt,
    uint32_t* __restrict__ part_cnt, double* __restrict__ part_sum) {
  const int t = threadIdx.x;
  const int b = blockIdx.x / BLOCKS_PER_ROW;
  const int inRow = blockIdx.x - b * BLOCKS_PER_ROW;
  const int hw = inRow * 1024 + t * 4;
  const float* yb = yhat + (size_t)b * 3 * HW + hw;
  const float* tb = yt   + (size_t)b * 3 * HW + hw;
  float dp[4];
  dp4(yb, tb, dp);
  const float thMin = acosf(CHIF);   // matches reference's clamped-theta value
  uint32_t cnt = 0;
  float fsum = 0.f;
#pragma unroll
  for (int j = 0; j < 4; j++) {
    float d = dp[j];
    if (d >= CHIF) {                 // clamped-high point mass
      cnt++; fsum += thMin;
    } else if (d > SPLITF) {         // only region where acos can matter
      float th = acosf(d);           // no clamp needed: SPLIT < d < CHI
      if (th < THRESHF) { cnt++; fsum += th; }
    }
  }
  double s = (double)fsum;
  for (int off = 32; off; off >>= 1) {
    cnt += __shfl_down(cnt, off);
    s   += __shfl_down(s, off);
  }
  __shared__ uint32_t s_c[4];
  __shared__ double   s_s[4];
  const int wave = t >> 6, lane = t & 63;
  if (lane == 0) { s_c[wave] = cnt; s_s[wave] = s; }
  __syncthreads();
  if (t == 0) {
    part_cnt[blockIdx.x] = s_c[0] + s_c[1] + s_c[2] + s_c[3];
    part_sum[blockIdx.x] = s_s[0] + s_s[1] + s_s[2] + s_s[3];
  }
}

// Finish: one block per row. cond = (#{v<T} > PID)  <=>  vals[pid] < T (exact,
// tie-safe). cond false -> row answer is sum(v<T) (already reduced). cond true
// -> exact in-block 3-level radix select of vals[PID] (recomputing theta from
// inputs; no global sync needed since one workgroup owns the whole row).
__global__ __launch_bounds__(1024) void ep_finish(
    const float* __restrict__ yhat, const float* __restrict__ yt,
    const uint32_t* __restrict__ part_cnt, const double* __restrict__ part_sum,
    double* __restrict__ row_val) {
  const int b = blockIdx.x;
  const int t = threadIdx.x;
  const int w = t >> 6, lane = t & 63;       // 16 waves of 64

  // Phase A: reduce this row's 192 partials
  uint32_t c = 0; double s = 0.0;
  if (t < BLOCKS_PER_ROW) {
    c = part_cnt[b * BLOCKS_PER_ROW + t];
    s = part_sum[b * BLOCKS_PER_ROW + t];
  }
  for (int off = 32; off; off >>= 1) {
    c += __shfl_down(c, off);
    s += __shfl_down(s, off);
  }
  __shared__ uint32_t scl[16];
  __shared__ double   sdl[16];
  if (lane == 0) { scl[w] = c; sdl[w] = s; }
  __shared__ uint32_t sh_cnt;
  __shared__ double   sh_sum;
  __syncthreads();
  if (t == 0) {
    uint32_t C = 0; double S = 0.0;
    for (int i = 0; i < 16; i++) { C += scl[i]; S += sdl[i]; }
    sh_cnt = C; sh_sum = S;
  }
  __syncthreads();
  const bool cond = sh_cnt > PID;
  if (!cond) {
    if (t == 0) row_val[b] = sh_sum;
    return;
  }

  // Rare path: exact k-th (k=PID) order statistic of this row's thetas.
  const float* yb = yhat + (size_t)b * 3 * HW;
  const float* tb = yt   + (size_t)b * 3 * HW;
  __shared__ uint32_t hc[2048];
  __shared__ uint32_t lsc[1024];
  __shared__ uint32_t sh_prefix, sh_krem, sh_cless;
  if (t == 0) { sh_prefix = 0u; sh_krem = PID; sh_cless = 0u; }

  const int shifts[3] = {21, 10, 0};
  const int nbv[3]    = {2048, 2048, 1024};
  const int mshift[3] = {32, 21, 10};      // bits above current digit
  for (int lev = 0; lev < 3; lev++) {
    const int shift = shifts[lev];
    const int nbins = nbv[lev];
    for (int i = t; i < nbins; i += 1024) hc[i] = 0;
    __syncthreads();                        // also publishes sh_* updates
    const uint32_t pref = sh_prefix;
    const uint32_t k    = sh_krem;
    for (int p = t * 4; p < HW; p += 4096) {
      float th[4];
      theta4(yb + p, tb + p, th);
#pragma unroll
      for (int j = 0; j < 4; j++) {
        uint32_t key = f2key(th[j]);
        bool m = (lev == 0) || ((key >> mshift[lev]) == (pref >> mshift[lev]));
        if (m) atomicAdd(&hc[(key >> shift) & (nbins - 1)], 1u);
      }
    }
    __syncthreads();
    const int bpt = nbins >> 10;            // 2 or 1 bins per thread
    const int base = t * bpt;
    uint32_t csum = 0;
    for (int i = 0; i < bpt; i++) csum += hc[base + i];
    lsc[t] = csum;
    __syncthreads();
    uint32_t ci = csum;
    for (int off = 1; off < 1024; off <<= 1) {
      uint32_t cp = (t >= off) ? lsc[t - off] : 0;
      __syncthreads();
      ci += cp;
      lsc[t] = ci;
      __syncthreads();
    }
    const uint32_t cumBefore = ci - csum;
    if (k >= cumBefore && k < ci) {         // unique owner thread
      uint32_t cb = cumBefore;
      int sel = base;
      for (int i = 0; i < bpt; i++) {
        uint32_t cc = hc[base + i];
        if (cb + cc > k) { sel = base + i; break; }
        cb += cc;
      }
      sh_krem   = k - cb;
      sh_cless += cb;                       // owner-only RMW, barrier-separated
      sh_prefix = pref | ((uint32_t)sel << shift);
    }
    __syncthreads();
  }
  const uint32_t keystar  = sh_prefix;      // exact key of vals[PID]
  const uint32_t cnt_less = sh_cless;       // #{key < keystar}

  // Sum of values strictly below vals[PID]
  double sl = 0.0;
  for (int p = t * 4; p < HW; p += 4096) {
    float th[4];
    theta4(yb + p, tb + p, th);
#pragma unroll
    for (int j = 0; j < 4; j++)
      if (f2key(th[j]) < keystar) sl += (double)th[j];
  }
  for (int off = 32; off; off >>= 1) sl += __shfl_down(sl, off);
  if (lane == 0) sdl[w] = sl;
  __syncthreads();
  if (t == 0) {
    double SL = 0.0;
    for (int i = 0; i < 16; i++) SL += sdl[i];
    row_val[b] = SL + (double)(PID - cnt_less) * (double)key2f(keystar);
  }
}

// Combine 32 row values into the scalar output (one wave).
__global__ void ep_out(const double* __restrict__ row_val,
                       float* __restrict__ out) {
  const int lane = threadIdx.x;             // 64 threads = 1 wave
  double v = (lane < NBATCH) ? row_val[lane] : 0.0;
  for (int off = 32; off; off >>= 1) v += __shfl_down(v, off);
  if (lane == 0) out[0] = (float)v;
}

extern "C" void kernel_launch(void* const* d_in, const int* in_sizes, int n_in,
                              void* d_out, int out_size, void* d_ws, size_t ws_size,
                              hipStream_t stream) {
  const float* yhat = (const float*)d_in[0];
  const float* yt   = (const float*)d_in[1];
  float* out = (float*)d_out;

  // ws layout (all slots written before read -> no memset needed):
  //   part_sum[6144] f64 | row_val[32] f64 | part_cnt[6144] u32
  char* w = (char*)d_ws;
  double*   part_sum = (double*)w;
  double*   row_val  = part_sum + NBLOCKS;
  uint32_t* part_cnt = (uint32_t*)(row_val + NBATCH);

  ep_pass0 <<<NBLOCKS, 256, 0, stream>>>(yhat, yt, part_cnt, part_sum);
  ep_finish<<<NBATCH, 1024, 0, stream>>>(yhat, yt, part_cnt, part_sum, row_val);
  ep_out   <<<1, 64, 0, stream>>>(row_val, out);
}